// Round 1
// baseline (1145.624 us; speedup 1.0000x reference)
//
#include <hip/hip_runtime.h>

#define SEQ 640
#define BATCH 40
#define D_IN 8
#define D_TRAJ 32
#define D_LSTM 64
#define G4 256        // 4 * D_LSTM
#define NH 4
#define DH 48
#define EMB 192

__device__ __forceinline__ float sigmoid_f(float x) {
    return 1.f / (1.f + __expf(-x));
}
__device__ __forceinline__ float tanh_f(float x) {
    // robust: 1 - 2/(e^{2x}+1); handles +-inf of __expf
    float e = __expf(2.f * x);
    return 1.f - 2.f / (e + 1.f);
}

// ---------------------------------------------------------------------------
// Kernel 1: trajectory embed (ELU) + input-side LSTM gate precompute
// gates_x[t][b][g] = b_ih[g] + b_hh[g] + sum_h elu(hist[t][b]@W1.T + b1)[h] * W_ih[g][h]
// grid: 640 blocks (t), 256 threads
// ---------------------------------------------------------------------------
__global__ void __launch_bounds__(256) k_embed(
    const float* __restrict__ hist, const float* __restrict__ W1,
    const float* __restrict__ b1, const float* __restrict__ W_ih,
    const float* __restrict__ b_ih, const float* __restrict__ b_hh,
    float* __restrict__ gates_x)
{
    __shared__ float sh_hist[BATCH * D_IN];     // 320
    __shared__ float sh_traj[BATCH * D_TRAJ];   // 1280
    const int t = blockIdx.x, tid = threadIdx.x;

    for (int i = tid; i < BATCH * D_IN; i += 256)
        sh_hist[i] = hist[t * BATCH * D_IN + i];
    __syncthreads();

    for (int idx = tid; idx < BATCH * D_TRAJ; idx += 256) {
        int b = idx >> 5, h = idx & 31;
        float acc = b1[h];
        #pragma unroll
        for (int f = 0; f < D_IN; ++f)
            acc += sh_hist[b * D_IN + f] * W1[h * D_IN + f];
        sh_traj[idx] = acc > 0.f ? acc : (__expf(acc) - 1.f);   // ELU
    }
    __syncthreads();

    // one gate per thread, loop over batch
    float w[D_TRAJ];
    #pragma unroll
    for (int h = 0; h < D_TRAJ; ++h) w[h] = W_ih[tid * D_TRAJ + h];
    const float bias = b_ih[tid] + b_hh[tid];

    for (int b = 0; b < BATCH; ++b) {
        float acc = bias;
        #pragma unroll
        for (int h = 0; h < D_TRAJ; ++h)
            acc += sh_traj[b * D_TRAJ + h] * w[h];
        gates_x[(t * BATCH + b) * G4 + tid] = acc;   // coalesced
    }
}

// ---------------------------------------------------------------------------
// Kernel 2: LSTM recurrence. One block per batch element (40 independent
// chains). 256 threads = one gate each; W_hh row in registers; h in LDS
// (broadcast reads). gate order i,f,g,o.
// ---------------------------------------------------------------------------
__global__ void __launch_bounds__(256) k_lstm(
    const float* __restrict__ gates_x, const float* __restrict__ W_hh,
    float* __restrict__ seq_out)
{
    const int b = blockIdx.x, tid = threadIdx.x;
    __shared__ float h_lds[D_LSTM];
    __shared__ float g_lds[G4];

    float w[D_LSTM];
    #pragma unroll
    for (int k = 0; k < D_LSTM; ++k) w[k] = W_hh[tid * D_LSTM + k];

    if (tid < D_LSTM) h_lds[tid] = 0.f;
    float c = 0.f;
    __syncthreads();

    const float* gx = gates_x + b * G4 + tid;   // stride per t = 40*256
    float gx_cur = gx[0];
    float gx_n1  = gx[BATCH * G4];

    for (int t = 0; t < SEQ; ++t) {
        float gx_n2 = 0.f;
        if (t < SEQ - 2) gx_n2 = gx[(t + 2) * BATCH * G4];   // prefetch dist 2

        float a0 = gx_cur, a1 = 0.f, a2 = 0.f, a3 = 0.f;
        #pragma unroll
        for (int k = 0; k < D_LSTM; k += 4) {
            a0 += h_lds[k]     * w[k];
            a1 += h_lds[k + 1] * w[k + 1];
            a2 += h_lds[k + 2] * w[k + 2];
            a3 += h_lds[k + 3] * w[k + 3];
        }
        g_lds[tid] = (a0 + a1) + (a2 + a3);
        __syncthreads();

        if (tid < D_LSTM) {
            float gi = g_lds[tid];
            float gf = g_lds[64 + tid];
            float gg = g_lds[128 + tid];
            float go = g_lds[192 + tid];
            c = sigmoid_f(gf) * c + sigmoid_f(gi) * tanh_f(gg);
            float h = sigmoid_f(go) * tanh_f(c);
            h_lds[tid] = h;
            seq_out[(t * BATCH + b) * D_LSTM + tid] = h;
        }
        __syncthreads();

        gx_cur = gx_n1;
        gx_n1 = gx_n2;
    }
}

// ---------------------------------------------------------------------------
// Kernel 3: multi-head attention over the 40-agent axis, per (head, t).
// grid: dim3(4, 640), 256 threads. Writes per-head o slice to ws.
// ---------------------------------------------------------------------------
#define SQK 49   // padded row stride for q/k/v in LDS (break 48-stride conflicts)
__global__ void __launch_bounds__(256) k_attn(
    const float* __restrict__ seq,
    const float* __restrict__ Wq, const float* __restrict__ bq,
    const float* __restrict__ Wk, const float* __restrict__ bk,
    const float* __restrict__ Wv, const float* __restrict__ bv,
    float* __restrict__ o_buf)
{
    const int h = blockIdx.x, t = blockIdx.y, tid = threadIdx.x;
    __shared__ float sseq[BATCH * D_LSTM];   // 2560
    __shared__ float sq[BATCH * SQK];        // 1960
    __shared__ float sk[BATCH * SQK];
    __shared__ float sv[BATCH * SQK];
    __shared__ float ss[BATCH * 41];         // scores, padded

    for (int i = tid; i < BATCH * D_LSTM; i += 256)
        sseq[i] = seq[t * BATCH * D_LSTM + i];
    __syncthreads();

    // q/k/v head slices: 3 * 1920 outputs, each a 64-dot
    for (int m = 0; m < 3; ++m) {
        const float* W    = (m == 0) ? Wq : (m == 1) ? Wk : Wv;
        const float* bias = (m == 0) ? bq : (m == 1) ? bk : bv;
        float* dst        = (m == 0) ? sq : (m == 1) ? sk : sv;
        for (int r = tid; r < BATCH * DH; r += 256) {
            int bi = r / DH, d = r % DH;
            int e = h * DH + d;
            const float* wrow = W + e * D_LSTM;
            const float* srow = sseq + bi * D_LSTM;
            float acc = bias[e];
            #pragma unroll 16
            for (int k = 0; k < D_LSTM; ++k) acc += srow[k] * wrow[k];
            dst[bi * SQK + d] = acc;
        }
    }
    __syncthreads();

    // scores = q k^T / 8
    for (int idx = tid; idx < BATCH * BATCH; idx += 256) {
        int i = idx / BATCH, j = idx % BATCH;
        float acc = 0.f;
        #pragma unroll 12
        for (int d = 0; d < DH; ++d) acc += sq[i * SQK + d] * sk[j * SQK + d];
        ss[i * 41 + j] = acc * 0.125f;
    }
    __syncthreads();

    // row softmax (one thread per row)
    if (tid < BATCH) {
        float m = -1e30f;
        for (int j = 0; j < BATCH; ++j) m = fmaxf(m, ss[tid * 41 + j]);
        float s = 0.f;
        for (int j = 0; j < BATCH; ++j) {
            float e = __expf(ss[tid * 41 + j] - m);
            ss[tid * 41 + j] = e;
            s += e;
        }
        float inv = 1.f / s;
        for (int j = 0; j < BATCH; ++j) ss[tid * 41 + j] *= inv;
    }
    __syncthreads();

    // o_h = a @ v ; write head slice into o_buf[t][b][h*48+d]
    for (int r = tid; r < BATCH * DH; r += 256) {
        int bi = r / DH, d = r % DH;
        float acc = 0.f;
        #pragma unroll 10
        for (int j = 0; j < BATCH; ++j) acc += ss[bi * 41 + j] * sv[j * SQK + d];
        o_buf[(t * BATCH + bi) * EMB + h * DH + d] = acc;
    }
}

// ---------------------------------------------------------------------------
// Kernel 4: GLU + residual + LayerNorm, per t. 256 threads.
// GLU phase: j = tid>>2 (output channel), bq = tid&3 (batch group of 10).
// LN phase: wave w handles rows {w, w+4, ...}; 64-lane shuffle reduction.
// ---------------------------------------------------------------------------
__global__ void __launch_bounds__(256) k_glu_ln(
    const float* __restrict__ seq, const float* __restrict__ obuf,
    const float* __restrict__ Wa, const float* __restrict__ ba,
    const float* __restrict__ Wg, const float* __restrict__ bg,
    const float* __restrict__ gamma, const float* __restrict__ beta,
    float* __restrict__ out)
{
    const int t = blockIdx.x, tid = threadIdx.x;
    __shared__ float so[BATCH * 193];       // o_t padded (192 -> 193)
    __shared__ float sy[BATCH * 65];        // y padded
    __shared__ float sseq[BATCH * D_LSTM];

    const float* ot = obuf + t * BATCH * EMB;
    for (int i = tid; i < BATCH * EMB; i += 256)
        so[(i / EMB) * 193 + (i % EMB)] = ot[i];
    for (int i = tid; i < BATCH * D_LSTM; i += 256)
        sseq[i] = seq[t * BATCH * D_LSTM + i];
    __syncthreads();

    const int j = tid >> 2, bgr = tid & 3;
    float acc_a[10], acc_g[10];
    #pragma unroll
    for (int bb = 0; bb < 10; ++bb) { acc_a[bb] = ba[j]; acc_g[bb] = bg[j]; }

    const float* wa = Wa + j * EMB;
    const float* wg = Wg + j * EMB;
    for (int p = 0; p < EMB; ++p) {
        float a = wa[p], g = wg[p];
        #pragma unroll
        for (int bb = 0; bb < 10; ++bb) {
            float o = so[(bgr + 4 * bb) * 193 + p];
            acc_a[bb] += o * a;
            acc_g[bb] += o * g;
        }
    }
    #pragma unroll
    for (int bb = 0; bb < 10; ++bb) {
        int b = bgr + 4 * bb;
        float tv = acc_a[bb] * sigmoid_f(acc_g[bb]);
        sy[b * 65 + j] = sseq[b * D_LSTM + j] + tv;
    }
    __syncthreads();

    const int w = tid >> 6, lane = tid & 63;
    const float gm = gamma[lane], bt = beta[lane];
    for (int rr = 0; rr < 10; ++rr) {
        int b = w + 4 * rr;
        float y = sy[b * 65 + lane];
        float s1 = y, s2 = y * y;
        #pragma unroll
        for (int m = 1; m < 64; m <<= 1) {
            s1 += __shfl_xor(s1, m, 64);
            s2 += __shfl_xor(s2, m, 64);
        }
        float mu  = s1 * (1.f / 64.f);
        float var = s2 * (1.f / 64.f) - mu * mu;
        float inv = rsqrtf(var + 1e-5f);
        out[t * BATCH * D_LSTM + b * D_LSTM + lane] = (y - mu) * inv * gm + bt;
    }
}

// ---------------------------------------------------------------------------
extern "C" void kernel_launch(void* const* d_in, const int* in_sizes, int n_in,
                              void* d_out, int out_size, void* d_ws, size_t ws_size,
                              hipStream_t stream)
{
    const float* hist = (const float*)d_in[0];
    // d_in[1] adj: unused (use_spatial=False)
    const float* W1   = (const float*)d_in[2];
    const float* b1   = (const float*)d_in[3];
    const float* W_ih = (const float*)d_in[4];
    const float* W_hh = (const float*)d_in[5];
    const float* b_ih = (const float*)d_in[6];
    const float* b_hh = (const float*)d_in[7];
    const float* Wq   = (const float*)d_in[8];
    const float* bq   = (const float*)d_in[9];
    const float* Wk   = (const float*)d_in[10];
    const float* bk   = (const float*)d_in[11];
    const float* Wv   = (const float*)d_in[12];
    const float* bv   = (const float*)d_in[13];
    const float* Wa   = (const float*)d_in[14];
    const float* ba   = (const float*)d_in[15];
    const float* Wg   = (const float*)d_in[16];
    const float* bg   = (const float*)d_in[17];
    const float* gamma = (const float*)d_in[18];
    const float* beta  = (const float*)d_in[19];
    float* out = (float*)d_out;

    float* ws = (float*)d_ws;
    float* gates_x = ws;                                   // 640*40*256 = 6,553,600 f
    float* seq     = ws + 6553600;                         // 640*40*64  = 1,638,400 f
    float* obuf    = ws + 6553600 + 1638400;               // 640*40*192 = 4,915,200 f
                                                           // total 52.4 MB of ws

    hipLaunchKernelGGL(k_embed, dim3(SEQ), dim3(256), 0, stream,
                       hist, W1, b1, W_ih, b_ih, b_hh, gates_x);
    hipLaunchKernelGGL(k_lstm, dim3(BATCH), dim3(256), 0, stream,
                       gates_x, W_hh, seq);
    hipLaunchKernelGGL(k_attn, dim3(NH, SEQ), dim3(256), 0, stream,
                       seq, Wq, bq, Wk, bk, Wv, bv, obuf);
    hipLaunchKernelGGL(k_glu_ln, dim3(SEQ), dim3(256), 0, stream,
                       seq, obuf, Wa, ba, Wg, bg, gamma, beta, out);
}